// Round 2
// baseline (250.874 us; speedup 1.0000x reference)
//
#include <hip/hip_runtime.h>

#define NQ 8
#define NL 4

// ---------------------------------------------------------------------------
// Pre-kernel: build the 32 batch-independent Rot(phi,theta,omega) matrices
// into workspace: gmat[(layer*8+q)*8 + {u00r,u00i,u01r,u01i,u10r,u10i,u11r,u11i}]
// U = [[ep*ct, -conj(em)*st], [em*st, conj(ep)*ct]],
// ep = exp(-0.5i(phi+omega)), em = exp(-0.5i(phi-omega))
// ---------------------------------------------------------------------------
__global__ void prep_gates_kernel(const float* __restrict__ weights,
                                  float* __restrict__ gmat) {
    int i = threadIdx.x;
    if (i < NL * NQ) {
        const float* wp = weights + i * 4;
        float phi = wp[0], theta = wp[1], omega = wp[2];
        float ct = cosf(0.5f * theta), st = sinf(0.5f * theta);
        float ap = 0.5f * (phi + omega), am = 0.5f * (phi - omega);
        float epr = cosf(ap), epi = -sinf(ap);
        float emr = cosf(am), emi = -sinf(am);
        float* g = gmat + i * 8;
        g[0] = epr * ct;   g[1] = epi * ct;      // u00 = ep*ct
        g[2] = -emr * st;  g[3] = emi * st;      // u01 = -conj(em)*st
        g[4] = emr * st;   g[5] = emi * st;      // u10 = em*st
        g[6] = epr * ct;   g[7] = -epi * ct;     // u11 = conj(ep)*ct
    }
}

// ---------------------------------------------------------------------------
// Main simulator. 16 lanes per element, 16 complex amps per lane.
// Amplitude index a (8 bits): a = (sub<<4) | r, sub = lane&15, r = reg slot.
// Wire w acts on amplitude bit (7-w).
// ---------------------------------------------------------------------------
__global__ __launch_bounds__(256) void qsim_kernel(
        const float* __restrict__ x,
        const float* __restrict__ gmat,
        const float* __restrict__ fc_w,
        const float* __restrict__ fc_b,
        float* __restrict__ out) {

    const int tid  = threadIdx.x;
    const int sub  = tid & 15;          // amp bits 7..4 (sub bit j = amp bit 4+j)
    const int wl   = tid & 63;          // lane within wave
    const int elem = blockIdx.x * 16 + (tid >> 4);

    // ---- load x, compute cos/sin of half-angles ----
    const float4 x0 = reinterpret_cast<const float4*>(x + (size_t)elem * 8)[0];
    const float4 x1 = reinterpret_cast<const float4*>(x + (size_t)elem * 8)[1];
    float cw[8], sw[8];
    {
        float xs[8] = {x0.x, x0.y, x0.z, x0.w, x1.x, x1.y, x1.z, x1.w};
        #pragma unroll
        for (int w = 0; w < 8; ++w) {
            float h = 0.5f * xs[w];
            cw[w] = __cosf(h);
            sw[w] = __sinf(h);
        }
    }

    // ---- initial product state after RX embedding ----
    // amp[a] = (-i)^popc(a) * prod_b (bit_b(a) ? sw[7-b] : cw[7-b])
    float lane_mag = 1.0f;
    #pragma unroll
    for (int j = 0; j < 4; ++j) {                 // amp bit 4+j -> wire 3-j
        lane_mag *= ((sub >> j) & 1) ? sw[3 - j] : cw[3 - j];
    }
    const int lane_pop = __popc(sub) & 3;
    const float base_r = (lane_pop == 0) ? lane_mag : (lane_pop == 2 ? -lane_mag : 0.0f);
    const float base_i = (lane_pop == 1) ? -lane_mag : (lane_pop == 3 ? lane_mag : 0.0f);

    float sr[16], si[16];
    #pragma unroll
    for (int r = 0; r < 16; ++r) {                // reg bit j -> wire 7-j
        float m = ((r     ) & 1 ? sw[7] : cw[7]);
        m      *= ((r >> 1) & 1 ? sw[6] : cw[6]);
        m      *= ((r >> 2) & 1 ? sw[5] : cw[5]);
        m      *= ((r >> 3) & 1 ? sw[4] : cw[4]);
        const int p = __popc(r) & 3;              // compile-time constant
        float ar, ai;
        if (p == 0)      { ar =  m * base_r; ai =  m * base_i; }
        else if (p == 1) { ar =  m * base_i; ai = -m * base_r; }
        else if (p == 2) { ar = -m * base_r; ai = -m * base_i; }
        else             { ar = -m * base_i; ai =  m * base_r; }
        sr[r] = ar; si[r] = ai;
    }

    // ---- layers ----
    #pragma unroll 1
    for (int layer = 0; layer < NL; ++layer) {
        const float* G = gmat + layer * 64;

        // Rot gates on amp bits 7..4 (q = 0..3): cross-lane via shfl_xor
        #pragma unroll
        for (int q = 0; q < 4; ++q) {
            const float* g = G + q * 8;
            const int  kb   = 3 - q;
            const int  mask = 1 << kb;
            const bool hi   = (sub >> kb) & 1;
            const float cAr = hi ? g[6] : g[0];   // coeff on own amp
            const float cAi = hi ? g[7] : g[1];
            const float cBr = hi ? g[4] : g[2];   // coeff on partner amp
            const float cBi = hi ? g[5] : g[3];
            #pragma unroll
            for (int r = 0; r < 16; ++r) {
                float pr = __shfl_xor(sr[r], mask);
                float pi = __shfl_xor(si[r], mask);
                float ar = sr[r], ai = si[r];
                sr[r] = cAr * ar - cAi * ai + cBr * pr - cBi * pi;
                si[r] = cAr * ai + cAi * ar + cBr * pi + cBi * pr;
            }
        }

        // Rot gates on amp bits 3..0 (q = 4..7): in-register pairs
        #pragma unroll
        for (int q = 4; q < 8; ++q) {
            const float* g = G + q * 8;
            const float u00r = g[0], u00i = g[1], u01r = g[2], u01i = g[3];
            const float u10r = g[4], u10i = g[5], u11r = g[6], u11i = g[7];
            const int kbit = 1 << (7 - q);
            #pragma unroll
            for (int r0 = 0; r0 < 16; ++r0) {
                if (r0 & kbit) continue;
                const int r1 = r0 | kbit;
                float a0r = sr[r0], a0i = si[r0];
                float a1r = sr[r1], a1i = si[r1];
                sr[r0] = u00r*a0r - u00i*a0i + u01r*a1r - u01i*a1i;
                si[r0] = u00r*a0i + u00i*a0r + u01r*a1i + u01i*a1r;
                sr[r1] = u10r*a0r - u10i*a0i + u11r*a1r - u11i*a1i;
                si[r1] = u10r*a0i + u10i*a0r + u11r*a1i + u11i*a1r;
            }
        }

        // CNOTs (7,6),(6,5),(5,4) composed into ONE lane permutation.
        // src = f0(f1(f2(sub))): f2 flips sub bit0 if bit1 (CNOT wire2),
        // f1 flips bit1 if bit2 (wire1), f0 flips bit2 if bit3 (wire0)
        {
            int u = sub;
            u ^= (u >> 1) & 1;
            u ^= ((u >> 2) & 1) << 1;
            u ^= ((u >> 3) & 1) << 2;
            const int src = (wl & ~15) | u;
            #pragma unroll
            for (int r = 0; r < 16; ++r) {
                sr[r] = __shfl(sr[r], src);
                si[r] = __shfl(si[r], src);
            }
        }

        // CNOT wire3: control = sub bit0 (amp bit4), target = reg bit 3
        {
            const bool cc = (sub & 1);
            #pragma unroll
            for (int r = 0; r < 8; ++r) {
                float t0r = sr[r],     t0i = si[r];
                float t1r = sr[r + 8], t1i = si[r + 8];
                sr[r]     = cc ? t1r : t0r;  si[r]     = cc ? t1i : t0i;
                sr[r + 8] = cc ? t0r : t1r;  si[r + 8] = cc ? t0i : t1i;
            }
        }

        // CNOT wires 4,5,6 composed: compile-time register permutation
        // src = f4(f5(f6(r)))
        {
            float tr[16], ti[16];
            #pragma unroll
            for (int r = 0; r < 16; ++r) {
                int v = r ^ ((r >> 1) & 1);       // f6: flip bit0 if bit1
                v ^= ((v >> 2) & 1) << 1;         // f5: flip bit1 if bit2
                v ^= ((v >> 3) & 1) << 2;         // f4: flip bit2 if bit3
                tr[r] = sr[v]; ti[r] = si[v];
            }
            #pragma unroll
            for (int r = 0; r < 16; ++r) { sr[r] = tr[r]; si[r] = ti[r]; }
        }
    }

    // ---- measurement: z_w = sum_a p_a * (1 - 2*bit_{7-w}(a)) ----
    float tot = 0.0f, z4 = 0.0f, z5 = 0.0f, z6 = 0.0f, z7 = 0.0f;
    #pragma unroll
    for (int r = 0; r < 16; ++r) {
        float p = sr[r]*sr[r] + si[r]*si[r];
        tot += p;
        z4 += (r & 8) ? -p : p;                   // wire 4 -> amp bit 3
        z5 += (r & 4) ? -p : p;
        z6 += (r & 2) ? -p : p;
        z7 += (r & 1) ? -p : p;                   // wire 7 -> amp bit 0
    }
    float z[8];
    z[0] = (sub & 8) ? -tot : tot;                // wire 0 -> amp bit 7 (sub bit 3)
    z[1] = (sub & 4) ? -tot : tot;
    z[2] = (sub & 2) ? -tot : tot;
    z[3] = (sub & 1) ? -tot : tot;
    z[4] = z4; z[5] = z5; z[6] = z6; z[7] = z7;

    #pragma unroll
    for (int m = 1; m < 16; m <<= 1) {
        #pragma unroll
        for (int w = 0; w < 8; ++w) z[w] += __shfl_xor(z[w], m);
    }

    if (sub == 0) {
        #pragma unroll
        for (int c = 0; c < 3; ++c) {
            float o = fc_b[c];
            #pragma unroll
            for (int w = 0; w < 8; ++w) o += fc_w[c * 8 + w] * z[w];
            out[(size_t)elem * 3 + c] = o;
        }
    }
}

extern "C" void kernel_launch(void* const* d_in, const int* in_sizes, int n_in,
                              void* d_out, int out_size, void* d_ws, size_t ws_size,
                              hipStream_t stream) {
    const float* x       = (const float*)d_in[0];
    const float* weights = (const float*)d_in[1];
    const float* fc_w    = (const float*)d_in[2];
    const float* fc_b    = (const float*)d_in[3];
    float* out  = (float*)d_out;
    float* gmat = (float*)d_ws;          // 32 gates * 8 floats = 1 KiB

    const int batch = in_sizes[0] / NQ;  // 65536

    prep_gates_kernel<<<1, 64, 0, stream>>>(weights, gmat);
    qsim_kernel<<<batch / 16, 256, 0, stream>>>(x, gmat, fc_w, fc_b, out);
}

// Round 3
// 143.253 us; speedup vs baseline: 1.7513x; 1.7513x over previous
//
#include <hip/hip_runtime.h>

#define NQ 8
#define NL 4

typedef _Float16 half8 __attribute__((ext_vector_type(8)));
typedef float f32x4 __attribute__((ext_vector_type(4)));

// Persistent device-global scratch (avoids d_ws sizing concerns; rewritten
// every kernel_launch call, stream-ordered, graph-capture safe).
__device__ float    gmat_d[NL * NQ * 8];          // 32 gate matrices
__device__ float    wc_d[3 * 256];                // folded fc_w sign table
__device__ _Float16 A_pack_d[32 * 16 * 512];      // 512x512 f16, MFMA-frag-packed

// A_pack layout: frag(mt, ks) holds rows [mt*16,mt*16+16) x k [ks*32,ks*32+32)
// lane l supplies A[row = mt*16 + (l&15)][k = ks*32 + (l>>4)*8 + i], i=0..7
// ushort index = ((mt*16+ks)*64 + ((k_local>>3)<<4 | (row&15)))*8 + (k_local&7)
__device__ __forceinline__ int apack_idx(int row, int k) {
    return ((row >> 4) * 16 + (k >> 5)) * 512 + ((((k >> 3) & 3) << 4) | (row & 15)) * 8 + (k & 7);
}

// ---------------------------------------------------------------------------
// prep 1: gate matrices (32 threads) + wc table (256 threads)
// wc[c][a] = sum_w fc_w[c][w] * (1 - 2*bit_{7-w}(a))
// ---------------------------------------------------------------------------
__global__ void prep_gates_kernel(const float* __restrict__ weights,
                                  const float* __restrict__ fc_w) {
    int t = threadIdx.x;
    if (t < NL * NQ) {
        const float* wp = weights + t * 4;
        float phi = wp[0], theta = wp[1], omega = wp[2];
        float ct = cosf(0.5f * theta), st = sinf(0.5f * theta);
        float ap = 0.5f * (phi + omega), am = 0.5f * (phi - omega);
        float epr = cosf(ap), epi = -sinf(ap);
        float emr = cosf(am), emi = -sinf(am);
        float* g = gmat_d + t * 8;
        g[0] = epr * ct;   g[1] = epi * ct;
        g[2] = -emr * st;  g[3] = emi * st;
        g[4] = emr * st;   g[5] = emi * st;
        g[6] = epr * ct;   g[7] = -epi * ct;
    }
    #pragma unroll
    for (int c = 0; c < 3; ++c) {
        float s = 0.0f;
        #pragma unroll
        for (int w = 0; w < 8; ++w) {
            s += fc_w[c * 8 + w] * (((t >> (7 - w)) & 1) ? -1.0f : 1.0f);
        }
        wc_d[c * 256 + t] = s;
    }
}

// ---------------------------------------------------------------------------
// prep 2: build U (256x256 complex) by simulating the 4 layers on the 256
// basis states, using the round-2 VALU simulator structure (16 lanes/column).
// Store A_big = [[Ur,-Ui],[Ui,Ur]] (512x512) into A_pack_d as f16.
// ---------------------------------------------------------------------------
__global__ __launch_bounds__(256) void prep_unitary_kernel() {
    const int tid = threadIdx.x;
    const int sub = tid & 15;
    const int wl  = tid & 63;
    const int e   = blockIdx.x * 16 + (tid >> 4);   // basis column 0..255

    float sr[16], si[16];
    #pragma unroll
    for (int r = 0; r < 16; ++r) {
        sr[r] = ((sub * 16 + r) == e) ? 1.0f : 0.0f;
        si[r] = 0.0f;
    }

    #pragma unroll 1
    for (int layer = 0; layer < NL; ++layer) {
        const float* G = gmat_d + layer * 64;

        #pragma unroll
        for (int q = 0; q < 4; ++q) {
            const float* g = G + q * 8;
            const int  kb   = 3 - q;
            const int  mask = 1 << kb;
            const bool hi   = (sub >> kb) & 1;
            const float cAr = hi ? g[6] : g[0];
            const float cAi = hi ? g[7] : g[1];
            const float cBr = hi ? g[4] : g[2];
            const float cBi = hi ? g[5] : g[3];
            #pragma unroll
            for (int r = 0; r < 16; ++r) {
                float pr = __shfl_xor(sr[r], mask);
                float pi = __shfl_xor(si[r], mask);
                float ar = sr[r], ai = si[r];
                sr[r] = cAr * ar - cAi * ai + cBr * pr - cBi * pi;
                si[r] = cAr * ai + cAi * ar + cBr * pi + cBi * pr;
            }
        }

        #pragma unroll
        for (int q = 4; q < 8; ++q) {
            const float* g = G + q * 8;
            const float u00r = g[0], u00i = g[1], u01r = g[2], u01i = g[3];
            const float u10r = g[4], u10i = g[5], u11r = g[6], u11i = g[7];
            const int kbit = 1 << (7 - q);
            #pragma unroll
            for (int r0 = 0; r0 < 16; ++r0) {
                if (r0 & kbit) continue;
                const int r1 = r0 | kbit;
                float a0r = sr[r0], a0i = si[r0];
                float a1r = sr[r1], a1i = si[r1];
                sr[r0] = u00r*a0r - u00i*a0i + u01r*a1r - u01i*a1i;
                si[r0] = u00r*a0i + u00i*a0r + u01r*a1i + u01i*a1r;
                sr[r1] = u10r*a0r - u10i*a0i + u11r*a1r - u11i*a1i;
                si[r1] = u10r*a0i + u10i*a0r + u11r*a1i + u11i*a1r;
            }
        }

        {   // CNOT wires 0,1,2 -> lane permutation
            int u = sub;
            u ^= (u >> 1) & 1;
            u ^= ((u >> 2) & 1) << 1;
            u ^= ((u >> 3) & 1) << 2;
            const int src = (wl & ~15) | u;
            #pragma unroll
            for (int r = 0; r < 16; ++r) {
                sr[r] = __shfl(sr[r], src);
                si[r] = __shfl(si[r], src);
            }
        }
        {   // CNOT wire 3
            const bool cc = (sub & 1);
            #pragma unroll
            for (int r = 0; r < 8; ++r) {
                float t0r = sr[r],     t0i = si[r];
                float t1r = sr[r + 8], t1i = si[r + 8];
                sr[r]     = cc ? t1r : t0r;  si[r]     = cc ? t1i : t0i;
                sr[r + 8] = cc ? t0r : t1r;  si[r + 8] = cc ? t0i : t1i;
            }
        }
        {   // CNOT wires 4,5,6 -> register permutation
            float tr[16], ti[16];
            #pragma unroll
            for (int r = 0; r < 16; ++r) {
                int v = r ^ ((r >> 1) & 1);
                v ^= ((v >> 2) & 1) << 1;
                v ^= ((v >> 3) & 1) << 2;
                tr[r] = sr[v]; ti[r] = si[v];
            }
            #pragma unroll
            for (int r = 0; r < 16; ++r) { sr[r] = tr[r]; si[r] = ti[r]; }
        }
    }

    // store: U[a][e] = amp_a; quadrants of A_big
    #pragma unroll
    for (int r = 0; r < 16; ++r) {
        const int a  = sub * 16 + r;
        const float re = sr[r], im = si[r];
        A_pack_d[apack_idx(a,       e      )] = (_Float16)( re);  // Ur
        A_pack_d[apack_idx(a,       256 + e)] = (_Float16)(-im);  // -Ui
        A_pack_d[apack_idx(256 + a, e      )] = (_Float16)( im);  // Ui
        A_pack_d[apack_idx(256 + a, 256 + e)] = (_Float16)( re);  // Ur
    }
}

// ---------------------------------------------------------------------------
// Main: per WG of 256 threads handle 64 elements.
// Stage 1: build B = [sr(256); si(256)] x 64 (f16) in LDS, frag-packed.
// Stage 2: two passes p=0 (amp_r rows) / p=1 (amp_i rows): M=256,K=512 MFMA,
//          epilogue squares + wc-weighted reduce into 3 outputs per element.
// ---------------------------------------------------------------------------
__global__ __launch_bounds__(256) void qgemm_kernel(
        const float* __restrict__ x,
        const float* __restrict__ fc_b,
        float* __restrict__ out) {

    __shared__ _Float16 Bl[512 * 64];    // 64 KiB, frag-packed
    __shared__ float    wcl[3 * 256];    // 3 KiB
    __shared__ float    red[4 * 3 * 64]; // 3 KiB

    const int tid  = threadIdx.x;
    const int lane = tid & 63;
    const int wv   = tid >> 6;

    // ---- stage 1: build states ----
    {
        const int q = tid >> 6;          // amp-hi quarter handled by this wave
        const int e = tid & 63;          // element column
        const float* xe = x + ((size_t)blockIdx.x * 64 + e) * 8;
        float cs[8], sn[8];
        #pragma unroll
        for (int w = 0; w < 8; ++w) {
            float h = 0.5f * xe[w];
            cs[w] = __cosf(h);
            sn[w] = __sinf(h);
        }
        // lo products: amp bits 3..0 (wires 7..4), with (-i)^popc phase
        float lor[16], loi[16];
        #pragma unroll
        for (int l = 0; l < 16; ++l) {
            float m = ((l & 1) ? sn[7] : cs[7]) * ((l & 2) ? sn[6] : cs[6])
                    * ((l & 4) ? sn[5] : cs[5]) * ((l & 8) ? sn[4] : cs[4]);
            const int p = __builtin_popcount(l) & 3;
            lor[l] = (p == 0) ? m : (p == 2 ? -m : 0.0f);
            loi[l] = (p == 1) ? -m : (p == 3 ? m : 0.0f);
        }
        const int nt = e >> 4, ec = e & 15;
        #pragma unroll
        for (int hh = 0; hh < 4; ++hh) {
            const int h = q * 4 + hh;
            float m = ((h & 1) ? sn[3] : cs[3]) * ((h & 2) ? sn[2] : cs[2])
                    * ((h & 4) ? sn[1] : cs[1]) * ((h & 8) ? sn[0] : cs[0]);
            const int ph = (__popc(q) + __popc(hh)) & 3;
            const float hr = (ph == 0) ? m : (ph == 2 ? -m : 0.0f);
            const float hi = (ph == 1) ? -m : (ph == 3 ? m : 0.0f);
            #pragma unroll
            for (int hf = 0; hf < 2; ++hf) {
                half8 vr, vi;
                #pragma unroll
                for (int j = 0; j < 8; ++j) {
                    const int l = hf * 8 + j;
                    vr[j] = (_Float16)(hr * lor[l] - hi * loi[l]);
                    vi[j] = (_Float16)(hr * loi[l] + hi * lor[l]);
                }
                const int ksr = (h * 2 + hf) >> 2;          // k = h*16+hf*8
                const int lq  = (h * 2 + hf) & 3;
                const int lb  = lq * 16 + ec;
                *reinterpret_cast<half8*>(&Bl[((ksr     * 4 + nt) * 64 + lb) * 8]) = vr;
                *reinterpret_cast<half8*>(&Bl[(((ksr+8) * 4 + nt) * 64 + lb) * 8]) = vi;
            }
        }
        // stage wc table
        wcl[tid]       = wc_d[tid];
        wcl[256 + tid] = wc_d[256 + tid];
        wcl[512 + tid] = wc_d[512 + tid];
    }
    __syncthreads();

    // ---- stage 2: GEMM + fused epilogue ----
    float part[4][3];
    #pragma unroll
    for (int n = 0; n < 4; ++n)
        #pragma unroll
        for (int c = 0; c < 3; ++c) part[n][c] = 0.0f;

    const half8* Bl8 = reinterpret_cast<const half8*>(Bl);

    #pragma unroll 1
    for (int p = 0; p < 2; ++p) {
        const half8* Ap8 = reinterpret_cast<const half8*>(A_pack_d)
                         + ((p * 16 + wv * 4) * 16) * 64 + lane;
        f32x4 acc[4][4];
        #pragma unroll
        for (int m = 0; m < 4; ++m)
            #pragma unroll
            for (int n = 0; n < 4; ++n) acc[m][n] = (f32x4){0.f, 0.f, 0.f, 0.f};

        #pragma unroll 4
        for (int ks = 0; ks < 16; ++ks) {
            half8 av[4], bv[4];
            #pragma unroll
            for (int m = 0; m < 4; ++m) av[m] = Ap8[(m * 16 + ks) * 64];
            #pragma unroll
            for (int n = 0; n < 4; ++n) bv[n] = Bl8[(ks * 4 + n) * 64 + lane];
            #pragma unroll
            for (int m = 0; m < 4; ++m)
                #pragma unroll
                for (int n = 0; n < 4; ++n)
                    acc[m][n] = __builtin_amdgcn_mfma_f32_16x16x32_f16(av[m], bv[n], acc[m][n], 0, 0, 0);
        }

        // epilogue: square + weighted reduce (wc is p-independent: row & 255)
        #pragma unroll
        for (int m = 0; m < 4; ++m) {
            const int rbase = wv * 64 + m * 16 + ((lane >> 4) << 2);
            #pragma unroll
            for (int j = 0; j < 4; ++j) {
                const float w0 = wcl[rbase + j];
                const float w1 = wcl[256 + rbase + j];
                const float w2 = wcl[512 + rbase + j];
                #pragma unroll
                for (int n = 0; n < 4; ++n) {
                    const float v = acc[m][n][j];
                    const float sq = v * v;
                    part[n][0] += w0 * sq;
                    part[n][1] += w1 * sq;
                    part[n][2] += w2 * sq;
                }
            }
        }
    }

    // reduce over the 4 row-groups within the wave
    #pragma unroll
    for (int n = 0; n < 4; ++n)
        #pragma unroll
        for (int c = 0; c < 3; ++c) {
            part[n][c] += __shfl_xor(part[n][c], 16);
            part[n][c] += __shfl_xor(part[n][c], 32);
        }

    if (lane < 16) {
        #pragma unroll
        for (int n = 0; n < 4; ++n)
            #pragma unroll
            for (int c = 0; c < 3; ++c)
                red[wv * 192 + c * 64 + n * 16 + lane] = part[n][c];
    }
    __syncthreads();

    if (tid < 192) {
        const int c = tid >> 6, e = tid & 63;
        float s = red[c * 64 + e] + red[192 + c * 64 + e]
                + red[384 + c * 64 + e] + red[576 + c * 64 + e] + fc_b[c];
        out[((size_t)blockIdx.x * 64 + e) * 3 + c] = s;
    }
}

extern "C" void kernel_launch(void* const* d_in, const int* in_sizes, int n_in,
                              void* d_out, int out_size, void* d_ws, size_t ws_size,
                              hipStream_t stream) {
    const float* x       = (const float*)d_in[0];
    const float* weights = (const float*)d_in[1];
    const float* fc_w    = (const float*)d_in[2];
    const float* fc_b    = (const float*)d_in[3];
    float* out = (float*)d_out;

    const int batch = in_sizes[0] / NQ;   // 65536

    prep_gates_kernel<<<1, 256, 0, stream>>>(weights, fc_w);
    prep_unitary_kernel<<<16, 256, 0, stream>>>();
    qgemm_kernel<<<batch / 64, 256, 0, stream>>>(x, fc_b, out);
}

// Round 11
// 142.541 us; speedup vs baseline: 1.7600x; 1.0050x over previous
//
#include <hip/hip_runtime.h>

#define NQ 8
#define NL 4

typedef _Float16 half8 __attribute__((ext_vector_type(8)));
typedef float f32x4 __attribute__((ext_vector_type(4)));

// Persistent device-global scratch (avoids d_ws sizing concerns; rewritten
// every kernel_launch call, stream-ordered, graph-capture safe).
__device__ float    gmat_d[NL * NQ * 8];          // 32 gate matrices
__device__ float    wc_d[3 * 256];                // folded fc_w sign table
__device__ _Float16 A_pack_d[32 * 16 * 512];      // 512x512 f16, MFMA-frag-packed

// A_pack layout: frag(mt, ks) holds rows [mt*16,mt*16+16) x k [ks*32,ks*32+32)
// lane l supplies A[row = mt*16 + (l&15)][k = ks*32 + (l>>4)*8 + i], i=0..7
// ushort index = ((mt*16+ks)*64 + ((k_local>>3)<<4 | (row&15)))*8 + (k_local&7)
__device__ __forceinline__ int apack_idx(int row, int k) {
    return ((row >> 4) * 16 + (k >> 5)) * 512 + ((((k >> 3) & 3) << 4) | (row & 15)) * 8 + (k & 7);
}

// ---------------------------------------------------------------------------
// prep 1: gate matrices (32 threads) + wc table (256 threads)
// wc[c][a] = sum_w fc_w[c][w] * (1 - 2*bit_{7-w}(a))
// ---------------------------------------------------------------------------
__global__ void prep_gates_kernel(const float* __restrict__ weights,
                                  const float* __restrict__ fc_w) {
    int t = threadIdx.x;
    if (t < NL * NQ) {
        const float* wp = weights + t * 4;
        float phi = wp[0], theta = wp[1], omega = wp[2];
        float ct = cosf(0.5f * theta), st = sinf(0.5f * theta);
        float ap = 0.5f * (phi + omega), am = 0.5f * (phi - omega);
        float epr = cosf(ap), epi = -sinf(ap);
        float emr = cosf(am), emi = -sinf(am);
        float* g = gmat_d + t * 8;
        g[0] = epr * ct;   g[1] = epi * ct;
        g[2] = -emr * st;  g[3] = emi * st;
        g[4] = emr * st;   g[5] = emi * st;
        g[6] = epr * ct;   g[7] = -epi * ct;
    }
    #pragma unroll
    for (int c = 0; c < 3; ++c) {
        float s = 0.0f;
        #pragma unroll
        for (int w = 0; w < 8; ++w) {
            s += fc_w[c * 8 + w] * (((t >> (7 - w)) & 1) ? -1.0f : 1.0f);
        }
        wc_d[c * 256 + t] = s;
    }
}

// ---------------------------------------------------------------------------
// prep 2: build U (256x256 complex) by simulating the 4 layers on the 256
// basis states, using the round-2 VALU simulator structure (16 lanes/column).
// Store A_big = [[Ur,-Ui],[Ui,Ur]] (512x512) into A_pack_d as f16.
// ---------------------------------------------------------------------------
__global__ __launch_bounds__(256) void prep_unitary_kernel() {
    const int tid = threadIdx.x;
    const int sub = tid & 15;
    const int wl  = tid & 63;
    const int e   = blockIdx.x * 16 + (tid >> 4);   // basis column 0..255

    float sr[16], si[16];
    #pragma unroll
    for (int r = 0; r < 16; ++r) {
        sr[r] = ((sub * 16 + r) == e) ? 1.0f : 0.0f;
        si[r] = 0.0f;
    }

    #pragma unroll 1
    for (int layer = 0; layer < NL; ++layer) {
        const float* G = gmat_d + layer * 64;

        #pragma unroll
        for (int q = 0; q < 4; ++q) {
            const float* g = G + q * 8;
            const int  kb   = 3 - q;
            const int  mask = 1 << kb;
            const bool hi   = (sub >> kb) & 1;
            const float cAr = hi ? g[6] : g[0];
            const float cAi = hi ? g[7] : g[1];
            const float cBr = hi ? g[4] : g[2];
            const float cBi = hi ? g[5] : g[3];
            #pragma unroll
            for (int r = 0; r < 16; ++r) {
                float pr = __shfl_xor(sr[r], mask);
                float pi = __shfl_xor(si[r], mask);
                float ar = sr[r], ai = si[r];
                sr[r] = cAr * ar - cAi * ai + cBr * pr - cBi * pi;
                si[r] = cAr * ai + cAi * ar + cBr * pi + cBi * pr;
            }
        }

        #pragma unroll
        for (int q = 4; q < 8; ++q) {
            const float* g = G + q * 8;
            const float u00r = g[0], u00i = g[1], u01r = g[2], u01i = g[3];
            const float u10r = g[4], u10i = g[5], u11r = g[6], u11i = g[7];
            const int kbit = 1 << (7 - q);
            #pragma unroll
            for (int r0 = 0; r0 < 16; ++r0) {
                if (r0 & kbit) continue;
                const int r1 = r0 | kbit;
                float a0r = sr[r0], a0i = si[r0];
                float a1r = sr[r1], a1i = si[r1];
                sr[r0] = u00r*a0r - u00i*a0i + u01r*a1r - u01i*a1i;
                si[r0] = u00r*a0i + u00i*a0r + u01r*a1i + u01i*a1r;
                sr[r1] = u10r*a0r - u10i*a0i + u11r*a1r - u11i*a1i;
                si[r1] = u10r*a0i + u10i*a0r + u11r*a1i + u11i*a1r;
            }
        }

        {   // CNOT wires 0,1,2 -> lane permutation
            int u = sub;
            u ^= (u >> 1) & 1;
            u ^= ((u >> 2) & 1) << 1;
            u ^= ((u >> 3) & 1) << 2;
            const int src = (wl & ~15) | u;
            #pragma unroll
            for (int r = 0; r < 16; ++r) {
                sr[r] = __shfl(sr[r], src);
                si[r] = __shfl(si[r], src);
            }
        }
        {   // CNOT wire 3
            const bool cc = (sub & 1);
            #pragma unroll
            for (int r = 0; r < 8; ++r) {
                float t0r = sr[r],     t0i = si[r];
                float t1r = sr[r + 8], t1i = si[r + 8];
                sr[r]     = cc ? t1r : t0r;  si[r]     = cc ? t1i : t0i;
                sr[r + 8] = cc ? t0r : t1r;  si[r + 8] = cc ? t0i : t1i;
            }
        }
        {   // CNOT wires 4,5,6 -> register permutation
            float tr[16], ti[16];
            #pragma unroll
            for (int r = 0; r < 16; ++r) {
                int v = r ^ ((r >> 1) & 1);
                v ^= ((v >> 2) & 1) << 1;
                v ^= ((v >> 3) & 1) << 2;
                tr[r] = sr[v]; ti[r] = si[v];
            }
            #pragma unroll
            for (int r = 0; r < 16; ++r) { sr[r] = tr[r]; si[r] = ti[r]; }
        }
    }

    // store: U[a][e] = amp_a; quadrants of A_big
    #pragma unroll
    for (int r = 0; r < 16; ++r) {
        const int a  = sub * 16 + r;
        const float re = sr[r], im = si[r];
        A_pack_d[apack_idx(a,       e      )] = (_Float16)( re);  // Ur
        A_pack_d[apack_idx(a,       256 + e)] = (_Float16)(-im);  // -Ui
        A_pack_d[apack_idx(256 + a, e      )] = (_Float16)( im);  // Ui
        A_pack_d[apack_idx(256 + a, 256 + e)] = (_Float16)( re);  // Ur
    }
}

// ---------------------------------------------------------------------------
// Main: per WG of 256 threads handle 64 elements.
// Stage 1: build B = [sr(256); si(256)] x 64 (f16) in LDS, frag-packed.
// Stage 2: two passes p=0 (amp_r rows) / p=1 (amp_i rows): M=256,K=512 MFMA,
//          epilogue squares + wc-weighted reduce into 3 outputs per element.
// ---------------------------------------------------------------------------
__global__ __launch_bounds__(256) void qgemm_kernel(
        const float* __restrict__ x,
        const float* __restrict__ fc_b,
        float* __restrict__ out) {

    __shared__ _Float16 Bl[512 * 64];    // 64 KiB, frag-packed
    __shared__ float    wcl[3 * 256];    // 3 KiB
    __shared__ float    red[4 * 3 * 64]; // 3 KiB

    const int tid  = threadIdx.x;
    const int lane = tid & 63;
    const int wv   = tid >> 6;

    // ---- stage 1: build states ----
    {
        const int q = tid >> 6;          // amp-hi quarter handled by this wave
        const int e = tid & 63;          // element column
        const float* xe = x + ((size_t)blockIdx.x * 64 + e) * 8;
        float cs[8], sn[8];
        #pragma unroll
        for (int w = 0; w < 8; ++w) {
            float h = 0.5f * xe[w];
            cs[w] = __cosf(h);
            sn[w] = __sinf(h);
        }
        // lo products: amp bits 3..0 (wires 7..4), with (-i)^popc phase
        float lor[16], loi[16];
        #pragma unroll
        for (int l = 0; l < 16; ++l) {
            float m = ((l & 1) ? sn[7] : cs[7]) * ((l & 2) ? sn[6] : cs[6])
                    * ((l & 4) ? sn[5] : cs[5]) * ((l & 8) ? sn[4] : cs[4]);
            const int p = __builtin_popcount(l) & 3;
            lor[l] = (p == 0) ? m : (p == 2 ? -m : 0.0f);
            loi[l] = (p == 1) ? -m : (p == 3 ? m : 0.0f);
        }
        const int nt = e >> 4, ec = e & 15;
        #pragma unroll
        for (int hh = 0; hh < 4; ++hh) {
            const int h = q * 4 + hh;
            float m = ((h & 1) ? sn[3] : cs[3]) * ((h & 2) ? sn[2] : cs[2])
                    * ((h & 4) ? sn[1] : cs[1]) * ((h & 8) ? sn[0] : cs[0]);
            const int ph = (__popc(q) + __popc(hh)) & 3;
            const float hr = (ph == 0) ? m : (ph == 2 ? -m : 0.0f);
            const float hi = (ph == 1) ? -m : (ph == 3 ? m : 0.0f);
            #pragma unroll
            for (int hf = 0; hf < 2; ++hf) {
                half8 vr, vi;
                #pragma unroll
                for (int j = 0; j < 8; ++j) {
                    const int l = hf * 8 + j;
                    vr[j] = (_Float16)(hr * lor[l] - hi * loi[l]);
                    vi[j] = (_Float16)(hr * loi[l] + hi * lor[l]);
                }
                const int ksr = (h * 2 + hf) >> 2;          // k = h*16+hf*8
                const int lq  = (h * 2 + hf) & 3;
                const int lb  = lq * 16 + ec;
                *reinterpret_cast<half8*>(&Bl[((ksr     * 4 + nt) * 64 + lb) * 8]) = vr;
                *reinterpret_cast<half8*>(&Bl[(((ksr+8) * 4 + nt) * 64 + lb) * 8]) = vi;
            }
        }
        // stage wc table
        wcl[tid]       = wc_d[tid];
        wcl[256 + tid] = wc_d[256 + tid];
        wcl[512 + tid] = wc_d[512 + tid];
    }
    __syncthreads();

    // ---- stage 2: GEMM + fused epilogue ----
    float part[4][3];
    #pragma unroll
    for (int n = 0; n < 4; ++n)
        #pragma unroll
        for (int c = 0; c < 3; ++c) part[n][c] = 0.0f;

    const half8* Bl8 = reinterpret_cast<const half8*>(Bl);

    #pragma unroll 1
    for (int p = 0; p < 2; ++p) {
        const half8* Ap8 = reinterpret_cast<const half8*>(A_pack_d)
                         + ((p * 16 + wv * 4) * 16) * 64 + lane;
        f32x4 acc[4][4];
        #pragma unroll
        for (int m = 0; m < 4; ++m)
            #pragma unroll
            for (int n = 0; n < 4; ++n) acc[m][n] = (f32x4){0.f, 0.f, 0.f, 0.f};

        #pragma unroll 4
        for (int ks = 0; ks < 16; ++ks) {
            half8 av[4], bv[4];
            #pragma unroll
            for (int m = 0; m < 4; ++m) av[m] = Ap8[(m * 16 + ks) * 64];
            #pragma unroll
            for (int n = 0; n < 4; ++n) bv[n] = Bl8[(ks * 4 + n) * 64 + lane];
            #pragma unroll
            for (int m = 0; m < 4; ++m)
                #pragma unroll
                for (int n = 0; n < 4; ++n)
                    acc[m][n] = __builtin_amdgcn_mfma_f32_16x16x32_f16(av[m], bv[n], acc[m][n], 0, 0, 0);
        }

        // epilogue: square + weighted reduce (wc is p-independent: row & 255)
        #pragma unroll
        for (int m = 0; m < 4; ++m) {
            const int rbase = wv * 64 + m * 16 + ((lane >> 4) << 2);
            #pragma unroll
            for (int j = 0; j < 4; ++j) {
                const float w0 = wcl[rbase + j];
                const float w1 = wcl[256 + rbase + j];
                const float w2 = wcl[512 + rbase + j];
                #pragma unroll
                for (int n = 0; n < 4; ++n) {
                    const float v = acc[m][n][j];
                    const float sq = v * v;
                    part[n][0] += w0 * sq;
                    part[n][1] += w1 * sq;
                    part[n][2] += w2 * sq;
                }
            }
        }
    }

    // reduce over the 4 row-groups within the wave
    #pragma unroll
    for (int n = 0; n < 4; ++n)
        #pragma unroll
        for (int c = 0; c < 3; ++c) {
            part[n][c] += __shfl_xor(part[n][c], 16);
            part[n][c] += __shfl_xor(part[n][c], 32);
        }

    if (lane < 16) {
        #pragma unroll
        for (int n = 0; n < 4; ++n)
            #pragma unroll
            for (int c = 0; c < 3; ++c)
                red[wv * 192 + c * 64 + n * 16 + lane] = part[n][c];
    }
    __syncthreads();

    if (tid < 192) {
        const int c = tid >> 6, e = tid & 63;
        float s = red[c * 64 + e] + red[192 + c * 64 + e]
                + red[384 + c * 64 + e] + red[576 + c * 64 + e] + fc_b[c];
        out[((size_t)blockIdx.x * 64 + e) * 3 + c] = s;
    }
}

extern "C" void kernel_launch(void* const* d_in, const int* in_sizes, int n_in,
                              void* d_out, int out_size, void* d_ws, size_t ws_size,
                              hipStream_t stream) {
    const float* x       = (const float*)d_in[0];
    const float* weights = (const float*)d_in[1];
    const float* fc_w    = (const float*)d_in[2];
    const float* fc_b    = (const float*)d_in[3];
    float* out = (float*)d_out;

    const int batch = in_sizes[0] / NQ;   // 65536

    prep_gates_kernel<<<1, 256, 0, stream>>>(weights, fc_w);
    prep_unitary_kernel<<<16, 256, 0, stream>>>();
    qgemm_kernel<<<batch / 64, 256, 0, stream>>>(x, fc_b, out);
}